// Round 6
// baseline (379.483 us; speedup 1.0000x reference)
//
#include <hip/hip_runtime.h>

// Problem constants
#define B_  32
#define M_  64
#define K_  36
#define DS_ 512
#define DX_ 128
#define DQ_ 512
#define H_  256

// kern1 grid layout: ROWS=8 per tile, in-block split-K=2 (512 threads)
#define S2B 512             // 256 tiles x 2 mats
#define PXB 144             // 1152/8 rows
#define QPB 32

// ---------------------------------------------------------------------------
// GEMM core: 8 rows x 256 cols, K = NCH*16 per K-half.
// A comes from LDS (uniform-address ds_read_b128 = broadcast, conflict-free,
// IN-ORDER lgkmcnt -> pipelinable, unlike s_load's out-of-order full-drain).
// W is per-lane global loads (vmcnt) with named double-buffer prefetch.
// ---------------------------------------------------------------------------
template<int NCH, int LDA>
__device__ __forceinline__ void gemm_lds8(const float* __restrict__ Ab,
                                          const float* __restrict__ Wp,
                                          float acc[8]) {
    float wA[16], wB[16];
    #pragma unroll
    for (int kk = 0; kk < 16; ++kk) wA[kk] = Wp[(size_t)kk * H_];

    #pragma unroll 1
    for (int s = 0; s < NCH; s += 2) {
        if (s + 1 < NCH) {               // prefetch chunk s+1 -> wB
            const float* Wn = Wp + (size_t)((s + 1) * 16) * H_;
            #pragma unroll
            for (int kk = 0; kk < 16; ++kk) wB[kk] = Wn[(size_t)kk * H_];
        }
        {                                // compute chunk s from wA (A via LDS)
            const float* Ac = Ab + s * 16;
            #pragma unroll
            for (int kq = 0; kq < 4; ++kq) {
                #pragma unroll
                for (int r = 0; r < 8; ++r) {
                    const float4 a =
                        *(const float4*)(Ac + (size_t)r * LDA + kq * 4);
                    acc[r] = fmaf(a.x, wA[kq * 4 + 0], acc[r]);
                    acc[r] = fmaf(a.y, wA[kq * 4 + 1], acc[r]);
                    acc[r] = fmaf(a.z, wA[kq * 4 + 2], acc[r]);
                    acc[r] = fmaf(a.w, wA[kq * 4 + 3], acc[r]);
                }
            }
        }
        if (s + 2 < NCH) {               // prefetch chunk s+2 -> wA
            const float* Wn = Wp + (size_t)((s + 2) * 16) * H_;
            #pragma unroll
            for (int kk = 0; kk < 16; ++kk) wA[kk] = Wn[(size_t)kk * H_];
        }
        if (s + 1 < NCH) {               // compute chunk s+1 from wB
            const float* Ac = Ab + (s + 1) * 16;
            #pragma unroll
            for (int kq = 0; kq < 4; ++kq) {
                #pragma unroll
                for (int r = 0; r < 8; ++r) {
                    const float4 a =
                        *(const float4*)(Ac + (size_t)r * LDA + kq * 4);
                    acc[r] = fmaf(a.x, wB[kq * 4 + 0], acc[r]);
                    acc[r] = fmaf(a.y, wB[kq * 4 + 1], acc[r]);
                    acc[r] = fmaf(a.z, wB[kq * 4 + 2], acc[r]);
                    acc[r] = fmaf(a.w, wB[kq * 4 + 3], acc[r]);
                }
            }
        }
    }
}

// ---------------------------------------------------------------------------
// kern1 (grid 688 x 512): all GEMMs, ROWS=8, in-block split-K=2.
//   blocks [0,512):     tile=bid>>1, mat=bid&1.
//       mat=0: pre_s[8 rows] = s2@w_s
//       mat=1: h1r[8 rows]   = relu(s2@h_w1 + h_b1)
//   blocks [512,656):   px[8 rows] = x0@w_x + score_b1   (K=128, halves 64)
//   blocks [656,688):   qpre[b]    = q[b]@w_q            (K=512, halves 256)
// A rows staged once in LDS (coalesced float4), W per-lane global loads.
// ---------------------------------------------------------------------------
__global__ __launch_bounds__(512, 4) void kern1(
    const float* __restrict__ s2,        // (2048,512)
    const float* __restrict__ x0,        // (1152,128)
    const float* __restrict__ q,         // (32,512)
    const float* __restrict__ score_w1,  // (1152,256)
    const float* __restrict__ score_b1,  // (256)
    const float* __restrict__ h_w1,      // (512,256)
    const float* __restrict__ h_b1,      // (256)
    float* __restrict__ pre_s,           // (2048,256)
    float* __restrict__ h1r,             // (2048,256) relu(h1+b1)
    float* __restrict__ px,              // (1152,256)
    float* __restrict__ qpre)            // (32,256)
{
    __shared__ float As[8 * DS_];        // 16 KB staged A rows
    __shared__ float comb[8 * H_];       // 8 KB split-K combine buffer
    const int t   = threadIdx.x;
    const int bid = blockIdx.x;
    const int h   = t & 255;
    const int kh  = __builtin_amdgcn_readfirstlane(t >> 8);   // wave-uniform

    if (bid < S2B) {                     // ---- s2 GEMMs ----
        const int tile = bid >> 1, mat = bid & 1;
        const float* W  = mat ? h_w1 : score_w1;              // (512,256)
        const float* Asrc = s2 + (size_t)tile * 8 * DS_;

        #pragma unroll
        for (int i = 0; i < 2; ++i) {    // stage 16 KB of A, coalesced
            const int flat = t * 4 + i * 2048;
            *(float4*)&As[flat] = *(const float4*)(Asrc + flat);
        }
        __syncthreads();

        const float* Wp = W + (size_t)(kh * 256) * H_ + h;
        const float* Ab = As + kh * 256;

        float acc[8];
        #pragma unroll
        for (int r = 0; r < 8; ++r) acc[r] = 0.f;

        gemm_lds8<16, DS_>(Ab, Wp, acc);

        if (kh) {
            #pragma unroll
            for (int r = 0; r < 8; ++r) comb[r * H_ + h] = acc[r];
        }
        __syncthreads();
        if (!kh) {
            if (!mat) {
                float* dst = pre_s + (size_t)tile * 8 * H_ + h;
                #pragma unroll
                for (int r = 0; r < 8; ++r)
                    dst[(size_t)r * H_] = acc[r] + comb[r * H_ + h];
            } else {
                const float b1v = h_b1[h];
                float* dst = h1r + (size_t)tile * 8 * H_ + h;
                #pragma unroll
                for (int r = 0; r < 8; ++r)
                    dst[(size_t)r * H_] =
                        fmaxf(acc[r] + comb[r * H_ + h] + b1v, 0.f);
            }
        }

    } else if (bid < S2B + PXB) {        // ---- px blocks (K=128) ----
        const int tile = bid - S2B;
        const float* Asrc = x0 + (size_t)tile * 8 * DX_;

        if (t < 256) {                   // stage 4 KB of A
            *(float4*)&As[t * 4] = *(const float4*)(Asrc + t * 4);
        }
        __syncthreads();

        const float* Wp = score_w1 + (size_t)(DS_ + kh * 64) * H_ + h;
        const float* Ab = As + kh * 64;

        float acc[8];
        #pragma unroll
        for (int r = 0; r < 8; ++r) acc[r] = 0.f;

        gemm_lds8<4, DX_>(Ab, Wp, acc);

        if (kh) {
            #pragma unroll
            for (int r = 0; r < 8; ++r) comb[r * H_ + h] = acc[r];
        }
        __syncthreads();
        if (!kh) {
            const float b1v = score_b1[h];
            float* dst = px + (size_t)tile * 8 * H_ + h;
            #pragma unroll
            for (int r = 0; r < 8; ++r)
                dst[(size_t)r * H_] = acc[r] + comb[r * H_ + h] + b1v;
        }

    } else {                             // ---- qpre blocks ----
        const int b = bid - (S2B + PXB);
        const float* Asrc = q + (size_t)b * DQ_;

        if (t < 128) {                   // stage 2 KB of q row
            *(float4*)&As[t * 4] = *(const float4*)(Asrc + t * 4);
        }
        __syncthreads();

        const float* qp = As + kh * 256;
        const float* wq = score_w1 + (size_t)(DS_ + DX_ + kh * 256) * H_ + h;
        float a0 = 0.f, a1 = 0.f, a2 = 0.f, a3 = 0.f;
        #pragma unroll 2
        for (int d = 0; d < 256; d += 4) {
            const float4 q4 = *(const float4*)(qp + d);
            a0 = fmaf(q4.x, wq[(size_t)(d + 0) * H_], a0);
            a1 = fmaf(q4.y, wq[(size_t)(d + 1) * H_], a1);
            a2 = fmaf(q4.z, wq[(size_t)(d + 2) * H_], a2);
            a3 = fmaf(q4.w, wq[(size_t)(d + 3) * H_], a3);
        }
        const float s = (a0 + a1) + (a2 + a3);
        if (kh) comb[h] = s;
        __syncthreads();
        if (!kh) qpre[(size_t)b * H_ + h] = s + comb[h];
    }
}

// ---------------------------------------------------------------------------
// kern2 (grid 256 x 256): hs = h1r @ h_w2   (2048x256 @ 256x128)
// 8 rows staged in LDS per block; each thread computes 4 rows for one f,
// amortizing the w2 loads 4x. LDS A-reads are wave-broadcast (free).
// ---------------------------------------------------------------------------
__global__ __launch_bounds__(256) void kern2(
    const float* __restrict__ h1r,       // (2048,256)
    const float* __restrict__ h_w2,      // (256,128)
    float* __restrict__ hs)              // (2048,128)
{
    __shared__ float A[8 * H_];          // 8 KB
    const int t  = threadIdx.x;
    const int r0 = blockIdx.x * 8;

    #pragma unroll
    for (int i = 0; i < 2; ++i) {
        const int flat = t * 4 + i * 1024;
        *(float4*)&A[flat] = *(const float4*)(h1r + (size_t)r0 * H_ + flat);
    }
    __syncthreads();

    const int f  = t & 127;
    const int rg = t >> 7;               // rows rg*4 .. rg*4+3
    const float* Ar  = &A[rg * 4 * H_];
    const float* w2p = h_w2 + f;

    float o0 = 0.f, o1 = 0.f, o2 = 0.f, o3 = 0.f;
    #pragma unroll 2
    for (int k = 0; k < H_; k += 4) {
        const float w0  = w2p[(size_t)(k + 0) * DX_];
        const float w1  = w2p[(size_t)(k + 1) * DX_];
        const float w2v = w2p[(size_t)(k + 2) * DX_];
        const float w3  = w2p[(size_t)(k + 3) * DX_];
        const float4 a0 = *(const float4*)&Ar[0 * H_ + k];
        const float4 a1 = *(const float4*)&Ar[1 * H_ + k];
        const float4 a2 = *(const float4*)&Ar[2 * H_ + k];
        const float4 a3 = *(const float4*)&Ar[3 * H_ + k];
        o0 = fmaf(a0.x, w0, o0); o0 = fmaf(a0.y, w1, o0);
        o0 = fmaf(a0.z, w2v, o0); o0 = fmaf(a0.w, w3, o0);
        o1 = fmaf(a1.x, w0, o1); o1 = fmaf(a1.y, w1, o1);
        o1 = fmaf(a1.z, w2v, o1); o1 = fmaf(a1.w, w3, o1);
        o2 = fmaf(a2.x, w0, o2); o2 = fmaf(a2.y, w1, o2);
        o2 = fmaf(a2.z, w2v, o2); o2 = fmaf(a2.w, w3, o2);
        o3 = fmaf(a3.x, w0, o3); o3 = fmaf(a3.y, w1, o3);
        o3 = fmaf(a3.z, w2v, o3); o3 = fmaf(a3.w, w3, o3);
    }
    float* dst = hs + ((size_t)r0 + rg * 4) * DX_ + f;
    dst[0 * DX_] = o0;
    dst[1 * DX_] = o1;
    dst[2 * DX_] = o2;
    dst[3 * DX_] = o3;
}

// ---------------------------------------------------------------------------
// kern3 (grid 1152 = one block per (b,k), 256 threads): logits+softmax+agg.
// Lane = h-quad (float4, coalesced); wave handles 16 m's with 6-step
// shfl_xor reduce; softmax in wave 0; agg reads precomputed hs.
// ---------------------------------------------------------------------------
__global__ __launch_bounds__(256) void kern3(
    const float* __restrict__ pre_s,     // (2048,256)
    const float* __restrict__ px,        // (1152,256)
    const float* __restrict__ qpre,      // (32,256)
    const float* __restrict__ score_w2,  // (256,1)
    const float* __restrict__ hs,        // (2048,128)
    const float* __restrict__ h_b2,      // (128)
    const float* __restrict__ x0,        // (1152,128)
    float* __restrict__ out)             // (1152,256)
{
    __shared__ float logit[M_];
    __shared__ float att[M_];
    __shared__ float pr[DX_];

    const int t    = threadIdx.x;
    const int bk   = blockIdx.x;
    const int b    = bk / K_;
    const int lane = t & 63, wave = t >> 6;
    const int hq   = lane << 2;          // h-quad base: 4 h's per lane

    float4 c4, v4;
    {
        const float4 qv = *(const float4*)(qpre + (size_t)b * H_ + hq);
        const float4 pv = *(const float4*)(px + (size_t)bk * H_ + hq);
        c4.x = qv.x + pv.x; c4.y = qv.y + pv.y;
        c4.z = qv.z + pv.z; c4.w = qv.w + pv.w;
        v4 = *(const float4*)(score_w2 + hq);
    }

    const float* ps = pre_s + (size_t)b * M_ * H_;
    #pragma unroll 2
    for (int mi = 0; mi < 16; ++mi) {
        const int m = wave * 16 + mi;
        const float4 p = *(const float4*)(ps + (size_t)m * H_ + hq);
        float x = fmaxf(p.x + c4.x, 0.f) * v4.x
                + fmaxf(p.y + c4.y, 0.f) * v4.y
                + fmaxf(p.z + c4.z, 0.f) * v4.z
                + fmaxf(p.w + c4.w, 0.f) * v4.w;
        #pragma unroll
        for (int off = 32; off > 0; off >>= 1)
            x += __shfl_xor(x, off, 64);
        if (lane == 0) logit[m] = x;
    }
    __syncthreads();

    if (wave == 0) {
        const float L = logit[lane];
        float mx = L;
        #pragma unroll
        for (int off = 32; off > 0; off >>= 1)
            mx = fmaxf(mx, __shfl_xor(mx, off, 64));
        const float e = expf(L - mx);
        float sm = e;
        #pragma unroll
        for (int off = 32; off > 0; off >>= 1)
            sm += __shfl_xor(sm, off, 64);
        att[lane] = e / sm;
    }
    __syncthreads();

    const int f = t & 127, mh = t >> 7;
    {
        const float* hsp = hs + ((size_t)b * M_ + mh * 32) * DX_ + f;
        float r = 0.f;
        #pragma unroll 4
        for (int m2 = 0; m2 < 32; ++m2)
            r = fmaf(att[mh * 32 + m2], hsp[(size_t)m2 * DX_], r);
        if (mh) pr[f] = r;
        __syncthreads();
        if (!mh)
            out[(size_t)bk * (2 * DX_) + DX_ + f] = r + pr[f] + h_b2[f];
    }
    if (t < DX_)
        out[(size_t)bk * (2 * DX_) + t] = x0[(size_t)bk * DX_ + t];
}

extern "C" void kernel_launch(void* const* d_in, const int* in_sizes, int n_in,
                              void* d_out, int out_size, void* d_ws, size_t ws_size,
                              hipStream_t stream) {
    (void)in_sizes; (void)n_in; (void)out_size; (void)ws_size;
    const float* s2       = (const float*)d_in[0];
    const float* x0       = (const float*)d_in[1];
    const float* q        = (const float*)d_in[2];
    const float* score_w1 = (const float*)d_in[3];
    const float* score_b1 = (const float*)d_in[4];
    const float* score_w2 = (const float*)d_in[5];
    // d_in[6] = score_b2 (cancels in softmax)
    const float* h_w1     = (const float*)d_in[7];
    const float* h_b1     = (const float*)d_in[8];
    const float* h_w2     = (const float*)d_in[9];
    const float* h_b2     = (const float*)d_in[10];
    float* out = (float*)d_out;

    float* ws    = (float*)d_ws;
    float* pre_s = ws;                                   // 2048*256
    float* h1r   = pre_s + (size_t)B_ * M_ * H_;         // 2048*256
    float* px    = h1r   + (size_t)B_ * M_ * H_;         // 1152*256
    float* qpre  = px    + (size_t)B_ * K_ * H_;         // 32*256
    float* hs    = qpre  + (size_t)B_ * H_;              // 2048*128

    kern1<<<S2B + PXB + QPB, 512, 0, stream>>>(
        s2, x0, q, score_w1, score_b1, h_w1, h_b1, pre_s, h1r, px, qpre);
    kern2<<<256, 256, 0, stream>>>(h1r, h_w2, hs);
    kern3<<<B_ * K_, 256, 0, stream>>>(pre_s, px, qpre, score_w2, hs, h_b2,
                                       x0, out);
}

// Round 7
// 131.098 us; speedup vs baseline: 2.8946x; 2.8946x over previous
//
#include <hip/hip_runtime.h>

// Problem constants
#define B_  32
#define M_  64
#define K_  36
#define DS_ 512
#define DX_ 128
#define DQ_ 512
#define H_  256

// kern1 grid: ROWS=4 per tile, in-block split-K=2 (512 threads)
#define S2B 1024            // 512 tiles x 2 mats
#define PXB 288             // 1152/4 rows
#define QPB 32

// ---------------------------------------------------------------------------
// kern1 (grid 1344 x 512): all GEMMs + fused hs. In-block split-K=2
// (waves 0-3 kh=0, waves 4-7 kh=1), LDS combine, single barriers.
// A rows staged in LDS (direct __shared__ indexing -> ds_read_b128
// broadcasts, in-order lgkmcnt, pipelinable). W per-lane global (vmcnt).
//   blocks [0,1024):    tile=bid>>1, mat=bid&1.
//     mat=0: pre_s[4 rows] = s2@w_s
//     mat=1: hs[4 rows] = relu(s2@h_w1 + h_b1) @ h_w2     (fused, in-block)
//   blocks [1024,1312): px[4 rows] = x0@w_x + score_b1    (K=128)
//   blocks [1312,1344): qpre[b]    = q[b]@w_q             (K=512)
// ---------------------------------------------------------------------------
__global__ __launch_bounds__(512, 6) void kern1(
    const float* __restrict__ s2,        // (2048,512)
    const float* __restrict__ x0,        // (1152,128)
    const float* __restrict__ q,         // (32,512)
    const float* __restrict__ score_w1,  // (1152,256)
    const float* __restrict__ score_b1,  // (256)
    const float* __restrict__ h_w1,      // (512,256)
    const float* __restrict__ h_b1,      // (256)
    const float* __restrict__ h_w2,      // (256,128)
    float* __restrict__ pre_s,           // (2048,256)
    float* __restrict__ px,              // (1152,256)
    float* __restrict__ qpre,            // (32,256)
    float* __restrict__ hs)              // (2048,128)
{
    __shared__ float As[4 * DS_];        // 8 KB staged A rows
    __shared__ float comb[4 * H_];       // 4 KB split-K combine
    __shared__ float hre[4 * H_];        // 4 KB relu'd h1 rows (mat=1)

    const int t   = threadIdx.x;
    const int bid = blockIdx.x;
    const int h   = t & 255;
    const int kh  = __builtin_amdgcn_readfirstlane(t >> 8);   // wave-uniform

    if (bid < S2B) {                     // ---- s2 GEMMs ----
        const int tile = bid >> 1, mat = bid & 1;
        const float* W = mat ? h_w1 : score_w1;               // (512,256)

        // stage 4 rows of s2 (8 KB), one float4 per thread, coalesced
        {
            const float* Asrc = s2 + (size_t)tile * 4 * DS_;
            *(float4*)&As[t * 4] = *(const float4*)(Asrc + t * 4);
        }
        __syncthreads();

        const float* Wp = W + (size_t)(kh * 256) * H_ + h;
        const int ab = kh * 256;         // wave-uniform A base within row

        float acc[4];
        #pragma unroll
        for (int r = 0; r < 4; ++r) acc[r] = 0.f;

        #pragma unroll 2
        for (int k = 0; k < 256; k += 4) {
            const float b0 = Wp[(size_t)(k + 0) * H_];
            const float b1 = Wp[(size_t)(k + 1) * H_];
            const float b2 = Wp[(size_t)(k + 2) * H_];
            const float b3 = Wp[(size_t)(k + 3) * H_];
            #pragma unroll
            for (int r = 0; r < 4; ++r) {
                const float4 a = *(const float4*)&As[r * DS_ + ab + k];
                acc[r] = fmaf(a.x, b0, acc[r]);
                acc[r] = fmaf(a.y, b1, acc[r]);
                acc[r] = fmaf(a.z, b2, acc[r]);
                acc[r] = fmaf(a.w, b3, acc[r]);
            }
        }

        if (kh) {
            #pragma unroll
            for (int r = 0; r < 4; ++r) comb[r * H_ + h] = acc[r];
        }
        __syncthreads();

        if (!mat) {                      // pre_s: plain store
            if (!kh) {
                float* dst = pre_s + (size_t)tile * 4 * H_ + h;
                #pragma unroll
                for (int r = 0; r < 4; ++r)
                    dst[(size_t)r * H_] = acc[r] + comb[r * H_ + h];
            }
        } else {                         // fused hs = relu(h1+b1) @ h_w2
            if (!kh) {
                const float b1v = h_b1[h];
                #pragma unroll
                for (int r = 0; r < 4; ++r)
                    hre[r * H_ + h] =
                        fmaxf(acc[r] + comb[r * H_ + h] + b1v, 0.f);
            }
            __syncthreads();

            const int row = t >> 7;      // 0..3 (wave-uniform)
            const int f   = t & 127;
            const float* w2p = h_w2 + f;
            float o0 = 0.f, o1 = 0.f, o2 = 0.f, o3 = 0.f;
            #pragma unroll 2
            for (int k = 0; k < H_; k += 4) {
                o0 = fmaf(hre[row * H_ + k + 0], w2p[(size_t)(k + 0) * DX_], o0);
                o1 = fmaf(hre[row * H_ + k + 1], w2p[(size_t)(k + 1) * DX_], o1);
                o2 = fmaf(hre[row * H_ + k + 2], w2p[(size_t)(k + 2) * DX_], o2);
                o3 = fmaf(hre[row * H_ + k + 3], w2p[(size_t)(k + 3) * DX_], o3);
            }
            hs[((size_t)tile * 4 + row) * DX_ + f] = (o0 + o1) + (o2 + o3);
        }

    } else if (bid < S2B + PXB) {        // ---- px blocks (K=128) ----
        const int tile = bid - S2B;

        if (t < 128) {                   // stage 4 rows of x0 (2 KB)
            const float* Asrc = x0 + (size_t)tile * 4 * DX_;
            *(float4*)&As[t * 4] = *(const float4*)(Asrc + t * 4);
        }
        __syncthreads();

        const float* Wp = score_w1 + (size_t)(DS_ + kh * 64) * H_ + h;
        const int ab = kh * 64;

        float acc[4];
        #pragma unroll
        for (int r = 0; r < 4; ++r) acc[r] = 0.f;

        #pragma unroll 2
        for (int k = 0; k < 64; k += 4) {
            const float b0 = Wp[(size_t)(k + 0) * H_];
            const float b1 = Wp[(size_t)(k + 1) * H_];
            const float b2 = Wp[(size_t)(k + 2) * H_];
            const float b3 = Wp[(size_t)(k + 3) * H_];
            #pragma unroll
            for (int r = 0; r < 4; ++r) {
                const float4 a = *(const float4*)&As[r * DX_ + ab + k];
                acc[r] = fmaf(a.x, b0, acc[r]);
                acc[r] = fmaf(a.y, b1, acc[r]);
                acc[r] = fmaf(a.z, b2, acc[r]);
                acc[r] = fmaf(a.w, b3, acc[r]);
            }
        }
        if (kh) {
            #pragma unroll
            for (int r = 0; r < 4; ++r) comb[r * H_ + h] = acc[r];
        }
        __syncthreads();
        if (!kh) {
            const float b1v = score_b1[h];
            float* dst = px + (size_t)tile * 4 * H_ + h;
            #pragma unroll
            for (int r = 0; r < 4; ++r)
                dst[(size_t)r * H_] = acc[r] + comb[r * H_ + h] + b1v;
        }

    } else {                             // ---- qpre blocks ----
        const int b = bid - (S2B + PXB);

        if (t < 128) {                   // stage q row (2 KB)
            const float* Asrc = q + (size_t)b * DQ_;
            *(float4*)&As[t * 4] = *(const float4*)(Asrc + t * 4);
        }
        __syncthreads();

        const float* wq = score_w1 + (size_t)(DS_ + DX_ + kh * 256) * H_ + h;
        const int qb = kh * 256;
        float a0 = 0.f, a1 = 0.f, a2 = 0.f, a3 = 0.f;
        #pragma unroll 2
        for (int d = 0; d < 256; d += 4) {
            const float4 q4 = *(const float4*)&As[qb + d];
            a0 = fmaf(q4.x, wq[(size_t)(d + 0) * H_], a0);
            a1 = fmaf(q4.y, wq[(size_t)(d + 1) * H_], a1);
            a2 = fmaf(q4.z, wq[(size_t)(d + 2) * H_], a2);
            a3 = fmaf(q4.w, wq[(size_t)(d + 3) * H_], a3);
        }
        const float s = (a0 + a1) + (a2 + a3);
        if (kh) comb[h] = s;
        __syncthreads();
        if (!kh) qpre[(size_t)b * H_ + h] = s + comb[h];
    }
}

// ---------------------------------------------------------------------------
// kern3 (grid 1152 = one block per (b,k), 256 threads): logits+softmax+agg.
// Lane = h-quad (float4, coalesced); wave handles 16 m's with 6-step
// shfl_xor reduce; softmax in wave 0; agg reads precomputed hs.
// (unchanged -- verified correct rounds 4-6)
// ---------------------------------------------------------------------------
__global__ __launch_bounds__(256) void kern3(
    const float* __restrict__ pre_s,     // (2048,256)
    const float* __restrict__ px,        // (1152,256)
    const float* __restrict__ qpre,      // (32,256)
    const float* __restrict__ score_w2,  // (256,1)
    const float* __restrict__ hs,        // (2048,128)
    const float* __restrict__ h_b2,      // (128)
    const float* __restrict__ x0,        // (1152,128)
    float* __restrict__ out)             // (1152,256)
{
    __shared__ float logit[M_];
    __shared__ float att[M_];
    __shared__ float pr[DX_];

    const int t    = threadIdx.x;
    const int bk   = blockIdx.x;
    const int b    = bk / K_;
    const int lane = t & 63, wave = t >> 6;
    const int hq   = lane << 2;          // h-quad base: 4 h's per lane

    float4 c4, v4;
    {
        const float4 qv = *(const float4*)(qpre + (size_t)b * H_ + hq);
        const float4 pv = *(const float4*)(px + (size_t)bk * H_ + hq);
        c4.x = qv.x + pv.x; c4.y = qv.y + pv.y;
        c4.z = qv.z + pv.z; c4.w = qv.w + pv.w;
        v4 = *(const float4*)(score_w2 + hq);
    }

    const float* ps = pre_s + (size_t)b * M_ * H_;
    #pragma unroll 2
    for (int mi = 0; mi < 16; ++mi) {
        const int m = wave * 16 + mi;
        const float4 p = *(const float4*)(ps + (size_t)m * H_ + hq);
        float x = fmaxf(p.x + c4.x, 0.f) * v4.x
                + fmaxf(p.y + c4.y, 0.f) * v4.y
                + fmaxf(p.z + c4.z, 0.f) * v4.z
                + fmaxf(p.w + c4.w, 0.f) * v4.w;
        #pragma unroll
        for (int off = 32; off > 0; off >>= 1)
            x += __shfl_xor(x, off, 64);
        if (lane == 0) logit[m] = x;
    }
    __syncthreads();

    if (wave == 0) {
        const float L = logit[lane];
        float mx = L;
        #pragma unroll
        for (int off = 32; off > 0; off >>= 1)
            mx = fmaxf(mx, __shfl_xor(mx, off, 64));
        const float e = expf(L - mx);
        float sm = e;
        #pragma unroll
        for (int off = 32; off > 0; off >>= 1)
            sm += __shfl_xor(sm, off, 64);
        att[lane] = e / sm;
    }
    __syncthreads();

    const int f = t & 127, mh = t >> 7;
    {
        const float* hsp = hs + ((size_t)b * M_ + mh * 32) * DX_ + f;
        float r = 0.f;
        #pragma unroll 4
        for (int m2 = 0; m2 < 32; ++m2)
            r = fmaf(att[mh * 32 + m2], hsp[(size_t)m2 * DX_], r);
        if (mh) pr[f] = r;
        __syncthreads();
        if (!mh)
            out[(size_t)bk * (2 * DX_) + DX_ + f] = r + pr[f] + h_b2[f];
    }
    if (t < DX_)
        out[(size_t)bk * (2 * DX_) + t] = x0[(size_t)bk * DX_ + t];
}

extern "C" void kernel_launch(void* const* d_in, const int* in_sizes, int n_in,
                              void* d_out, int out_size, void* d_ws, size_t ws_size,
                              hipStream_t stream) {
    (void)in_sizes; (void)n_in; (void)out_size; (void)ws_size;
    const float* s2       = (const float*)d_in[0];
    const float* x0       = (const float*)d_in[1];
    const float* q        = (const float*)d_in[2];
    const float* score_w1 = (const float*)d_in[3];
    const float* score_b1 = (const float*)d_in[4];
    const float* score_w2 = (const float*)d_in[5];
    // d_in[6] = score_b2 (cancels in softmax)
    const float* h_w1     = (const float*)d_in[7];
    const float* h_b1     = (const float*)d_in[8];
    const float* h_w2     = (const float*)d_in[9];
    const float* h_b2     = (const float*)d_in[10];
    float* out = (float*)d_out;

    float* ws    = (float*)d_ws;
    float* pre_s = ws;                                   // 2048*256
    float* px    = pre_s + (size_t)B_ * M_ * H_;         // 1152*256
    float* qpre  = px    + (size_t)B_ * K_ * H_;         // 32*256
    float* hs    = qpre  + (size_t)B_ * H_;              // 2048*128

    kern1<<<S2B + PXB + QPB, 512, 0, stream>>>(
        s2, x0, q, score_w1, score_b1, h_w1, h_b1, h_w2,
        pre_s, px, qpre, hs);
    kern3<<<B_ * K_, 256, 0, stream>>>(pre_s, px, qpre, score_w2, hs, h_b2,
                                       x0, out);
}